// Round 1
// baseline (4242.158 us; speedup 1.0000x reference)
//
#include <hip/hip_runtime.h>
#include <hip/hip_bf16.h>

#define N_NODES 500000
#define N_EDGES 8000000
#define HID 128
#define NPB 64      // nodes per block in MLP kernel
#define LDP 132     // padded LDS row (floats), 132*4B = 16B-aligned rows

// ---------------------------------------------------------------------------
// Workspace layout (bytes):
//   [0, 16,000,000)             agg   float[N_NODES*8]
//   [16,000,000, 18,000,000)    deg   float[N_NODES]
//   [18,000,000, 18,000,512)    colsum float[128]
// ---------------------------------------------------------------------------

__global__ __launch_bounds__(256) void k_scatter(
    const int* __restrict__ ei, const float4* __restrict__ x4,
    float* __restrict__ agg, float* __restrict__ deg)
{
    int e = blockIdx.x * 256 + threadIdx.x;
    if (e >= N_EDGES) return;
    int s = ei[e];             // src row
    int d = ei[N_EDGES + e];   // dst row
    atomicAdd(deg + s, 1.0f);
    float4 a = x4[(size_t)2 * d];
    float4 b = x4[(size_t)2 * d + 1];
    float* p = agg + (size_t)s * 8;
    atomicAdd(p + 0, a.x); atomicAdd(p + 1, a.y);
    atomicAdd(p + 2, a.z); atomicAdd(p + 3, a.w);
    atomicAdd(p + 4, b.x); atomicAdd(p + 5, b.y);
    atomicAdd(p + 6, b.z); atomicAdd(p + 7, b.w);
}

// 128->128 matvec for a 4-node x 8-col register tile, Hin from LDS, W from global
__device__ __forceinline__ void matvec128(
    const float (&Hin)[NPB][LDP],
    const float* __restrict__ W, const float* __restrict__ bias,
    int n0, int j0, float (&acc)[4][8])
{
    {
        float4 bb0 = *(const float4*)(bias + j0);
        float4 bb1 = *(const float4*)(bias + j0 + 4);
        #pragma unroll
        for (int r = 0; r < 4; ++r) {
            acc[r][0] = bb0.x; acc[r][1] = bb0.y; acc[r][2] = bb0.z; acc[r][3] = bb0.w;
            acc[r][4] = bb1.x; acc[r][5] = bb1.y; acc[r][6] = bb1.z; acc[r][7] = bb1.w;
        }
    }
    for (int k = 0; k < 128; k += 4) {
        float h[4][4];
        #pragma unroll
        for (int r = 0; r < 4; ++r) {
            float4 hv = *(const float4*)&Hin[n0 + r][k];
            h[r][0] = hv.x; h[r][1] = hv.y; h[r][2] = hv.z; h[r][3] = hv.w;
        }
        #pragma unroll
        for (int kk = 0; kk < 4; ++kk) {
            const float* wr = W + (size_t)(k + kk) * HID + j0;
            float4 w0 = *(const float4*)(wr);
            float4 w1 = *(const float4*)(wr + 4);
            float w[8] = {w0.x, w0.y, w0.z, w0.w, w1.x, w1.y, w1.z, w1.w};
            #pragma unroll
            for (int r = 0; r < 4; ++r) {
                float hv = h[r][kk];
                #pragma unroll
                for (int c = 0; c < 8; ++c)
                    acc[r][c] = fmaf(hv, w[c], acc[r][c]);
            }
        }
    }
}

__global__ __launch_bounds__(256, 2) void k_mlp(
    const float4* __restrict__ x4, const float4* __restrict__ agg4,
    const float* __restrict__ deg,
    const float* __restrict__ W1, const float* __restrict__ b1,
    const float* __restrict__ W2, const float* __restrict__ b2,
    const float* __restrict__ W3, const float* __restrict__ b3,
    float* __restrict__ colsum)
{
    __shared__ float A[NPB][LDP];
    __shared__ float B[NPB][LDP];
    __shared__ float csum[HID];

    int tid  = threadIdx.x;
    int cidx = tid & 15;      // 16 col groups
    int nidx = tid >> 4;      // 16 node groups
    int j0 = cidx * 8;
    int n0 = nidx * 4;
    int nbase = blockIdx.x * NPB;

    if (tid < HID) csum[tid] = 0.0f;

    // ---- layer 1: v = x + agg/deg (per-thread registers), h1 = relu(v@W1+b1) -> A
    float v[4][8];
    #pragma unroll
    for (int r = 0; r < 4; ++r) {
        int gn = nbase + n0 + r;
        if (gn < N_NODES) {
            float4 xa = x4[(size_t)2 * gn], xb = x4[(size_t)2 * gn + 1];
            float4 aa = agg4[(size_t)2 * gn], ab = agg4[(size_t)2 * gn + 1];
            float rd = 1.0f / fmaxf(deg[gn], 1.0f);
            v[r][0] = xa.x + aa.x * rd; v[r][1] = xa.y + aa.y * rd;
            v[r][2] = xa.z + aa.z * rd; v[r][3] = xa.w + aa.w * rd;
            v[r][4] = xb.x + ab.x * rd; v[r][5] = xb.y + ab.y * rd;
            v[r][6] = xb.z + ab.z * rd; v[r][7] = xb.w + ab.w * rd;
        } else {
            #pragma unroll
            for (int k = 0; k < 8; ++k) v[r][k] = 0.0f;
        }
    }
    float acc[4][8];
    {
        float4 bb0 = *(const float4*)(b1 + j0);
        float4 bb1 = *(const float4*)(b1 + j0 + 4);
        #pragma unroll
        for (int r = 0; r < 4; ++r) {
            acc[r][0] = bb0.x; acc[r][1] = bb0.y; acc[r][2] = bb0.z; acc[r][3] = bb0.w;
            acc[r][4] = bb1.x; acc[r][5] = bb1.y; acc[r][6] = bb1.z; acc[r][7] = bb1.w;
        }
    }
    #pragma unroll
    for (int k = 0; k < 8; ++k) {
        const float* wr = W1 + (size_t)k * HID + j0;
        float4 w0 = *(const float4*)(wr);
        float4 w1 = *(const float4*)(wr + 4);
        float w[8] = {w0.x, w0.y, w0.z, w0.w, w1.x, w1.y, w1.z, w1.w};
        #pragma unroll
        for (int r = 0; r < 4; ++r) {
            float hv = v[r][k];
            #pragma unroll
            for (int c = 0; c < 8; ++c) acc[r][c] = fmaf(hv, w[c], acc[r][c]);
        }
    }
    #pragma unroll
    for (int r = 0; r < 4; ++r) {
        float4 o0 = make_float4(fmaxf(acc[r][0], 0.f), fmaxf(acc[r][1], 0.f),
                                fmaxf(acc[r][2], 0.f), fmaxf(acc[r][3], 0.f));
        float4 o1 = make_float4(fmaxf(acc[r][4], 0.f), fmaxf(acc[r][5], 0.f),
                                fmaxf(acc[r][6], 0.f), fmaxf(acc[r][7], 0.f));
        *(float4*)&A[n0 + r][j0]     = o0;
        *(float4*)&A[n0 + r][j0 + 4] = o1;
    }
    __syncthreads();

    // ---- layer 2: h2 = relu(h1@W2+b2) -> B
    matvec128(A, W2, b2, n0, j0, acc);
    #pragma unroll
    for (int r = 0; r < 4; ++r) {
        float4 o0 = make_float4(fmaxf(acc[r][0], 0.f), fmaxf(acc[r][1], 0.f),
                                fmaxf(acc[r][2], 0.f), fmaxf(acc[r][3], 0.f));
        float4 o1 = make_float4(fmaxf(acc[r][4], 0.f), fmaxf(acc[r][5], 0.f),
                                fmaxf(acc[r][6], 0.f), fmaxf(acc[r][7], 0.f));
        *(float4*)&B[n0 + r][j0]     = o0;
        *(float4*)&B[n0 + r][j0 + 4] = o1;
    }
    __syncthreads();

    // ---- layer 3: h3 = relu(h2@W3+b3), reduced in registers (never stored)
    matvec128(B, W3, b3, n0, j0, acc);

    float part[8];
    #pragma unroll
    for (int c = 0; c < 8; ++c) part[c] = 0.0f;
    #pragma unroll
    for (int r = 0; r < 4; ++r) {
        if (nbase + n0 + r < N_NODES) {
            #pragma unroll
            for (int c = 0; c < 8; ++c) part[c] += fmaxf(acc[r][c], 0.f);
        }
    }
    #pragma unroll
    for (int c = 0; c < 8; ++c) atomicAdd(&csum[j0 + c], part[c]);
    __syncthreads();
    if (tid < HID) atomicAdd(colsum + tid, csum[tid]);
}

__global__ void k_final(const float* __restrict__ colsum,
                        const float* __restrict__ Wv, const float* __restrict__ bv,
                        float* __restrict__ out)
{
    __shared__ float red[2];
    int t = threadIdx.x;  // 128 threads
    float vv = colsum[t] * (1.0f / (float)N_NODES) * Wv[t];
    #pragma unroll
    for (int m = 32; m >= 1; m >>= 1) vv += __shfl_xor(vv, m, 64);
    if ((t & 63) == 0) red[t >> 6] = vv;
    __syncthreads();
    if (t == 0) out[0] = tanhf(red[0] + red[1] + bv[0]);
}

extern "C" void kernel_launch(void* const* d_in, const int* in_sizes, int n_in,
                              void* d_out, int out_size, void* d_ws, size_t ws_size,
                              hipStream_t stream)
{
    const float* x  = (const float*)d_in[0];
    const int*   ei = (const int*)d_in[1];
    const float* W1 = (const float*)d_in[2];
    const float* b1 = (const float*)d_in[3];
    const float* W2 = (const float*)d_in[4];
    const float* b2 = (const float*)d_in[5];
    const float* W3 = (const float*)d_in[6];
    const float* b3 = (const float*)d_in[7];
    const float* Wv = (const float*)d_in[8];
    const float* bv = (const float*)d_in[9];
    float* out = (float*)d_out;

    char* ws = (char*)d_ws;
    float* agg    = (float*)(ws);
    float* deg    = (float*)(ws + (size_t)N_NODES * 8 * 4);
    float* colsum = (float*)(ws + (size_t)N_NODES * 8 * 4 + (size_t)N_NODES * 4);
    size_t zero_bytes = (size_t)N_NODES * 8 * 4 + (size_t)N_NODES * 4 + HID * 4;

    hipMemsetAsync(d_ws, 0, zero_bytes, stream);

    k_scatter<<<(N_EDGES + 255) / 256, 256, 0, stream>>>(
        ei, (const float4*)x, agg, deg);

    k_mlp<<<(N_NODES + NPB - 1) / NPB, 256, 0, stream>>>(
        (const float4*)x, (const float4*)agg, deg,
        W1, b1, W2, b2, W3, b3, colsum);

    k_final<<<1, 128, 0, stream>>>(colsum, Wv, bv, out);
}

// Round 2
// 1439.645 us; speedup vs baseline: 2.9467x; 2.9467x over previous
//
#include <hip/hip_runtime.h>
#include <hip/hip_bf16.h>

#define N_NODES 500000
#define N_EDGES 8000000
#define HID 128
#define NPB 64      // nodes per block in MLP kernel
#define LDP 132     // padded LDS row (floats)
#define CAP 64      // adjacency row capacity (deg ~ Poisson(16); overflow handled exactly)

// ---------------------------------------------------------------------------
// Fast-path workspace layout (bytes), needs 146,000,512:
//   [0, 2,000,000)                cnt       int[N_NODES]        (zeroed)
//   [2,000,000, 2,000,512)        colsum    float[128]          (zeroed)
//   [2,000,512, 18,000,512)       agg_extra float[N_NODES*8]    (zeroed, overflow only)
//   [18,000,512, 146,000,512)     adj       int[N_NODES*CAP]    (no zero needed)
// Fallback layout (18,000,512 B): agg[N*8] | deg[N] | colsum[128]
// ---------------------------------------------------------------------------

// ---------------- fast path: adjacency build, 1 atomic per edge ------------
__global__ __launch_bounds__(256) void k_build(
    const int* __restrict__ ei, const float4* __restrict__ x4,
    int* __restrict__ cnt, int* __restrict__ adj, float* __restrict__ agg_extra)
{
    int e = blockIdx.x * 256 + threadIdx.x;
    if (e >= N_EDGES) return;
    int s = ei[e];
    int d = ei[N_EDGES + e];
    int pos = atomicAdd(cnt + s, 1);
    if (pos < CAP) {
        adj[(size_t)s * CAP + pos] = d;
    } else {
        // exact overflow path (statistically never taken for Poisson(16))
        float4 a = x4[(size_t)2 * d];
        float4 b = x4[(size_t)2 * d + 1];
        float* p = agg_extra + (size_t)s * 8;
        atomicAdd(p + 0, a.x); atomicAdd(p + 1, a.y);
        atomicAdd(p + 2, a.z); atomicAdd(p + 3, a.w);
        atomicAdd(p + 4, b.x); atomicAdd(p + 5, b.y);
        atomicAdd(p + 6, b.z); atomicAdd(p + 7, b.w);
    }
}

// ---------------- fallback path: original feature scatter ------------------
__global__ __launch_bounds__(256) void k_scatter(
    const int* __restrict__ ei, const float4* __restrict__ x4,
    float* __restrict__ agg, float* __restrict__ deg)
{
    int e = blockIdx.x * 256 + threadIdx.x;
    if (e >= N_EDGES) return;
    int s = ei[e];
    int d = ei[N_EDGES + e];
    atomicAdd(deg + s, 1.0f);
    float4 a = x4[(size_t)2 * d];
    float4 b = x4[(size_t)2 * d + 1];
    float* p = agg + (size_t)s * 8;
    atomicAdd(p + 0, a.x); atomicAdd(p + 1, a.y);
    atomicAdd(p + 2, a.z); atomicAdd(p + 3, a.w);
    atomicAdd(p + 4, b.x); atomicAdd(p + 5, b.y);
    atomicAdd(p + 6, b.z); atomicAdd(p + 7, b.w);
}

// 128->128 matvec for a 4-node x 8-col register tile, Hin from LDS, W from global
__device__ __forceinline__ void matvec128(
    const float (&Hin)[NPB][LDP],
    const float* __restrict__ W, const float* __restrict__ bias,
    int n0, int j0, float (&acc)[4][8])
{
    {
        float4 bb0 = *(const float4*)(bias + j0);
        float4 bb1 = *(const float4*)(bias + j0 + 4);
        #pragma unroll
        for (int r = 0; r < 4; ++r) {
            acc[r][0] = bb0.x; acc[r][1] = bb0.y; acc[r][2] = bb0.z; acc[r][3] = bb0.w;
            acc[r][4] = bb1.x; acc[r][5] = bb1.y; acc[r][6] = bb1.z; acc[r][7] = bb1.w;
        }
    }
    for (int k = 0; k < 128; k += 4) {
        float h[4][4];
        #pragma unroll
        for (int r = 0; r < 4; ++r) {
            float4 hv = *(const float4*)&Hin[n0 + r][k];
            h[r][0] = hv.x; h[r][1] = hv.y; h[r][2] = hv.z; h[r][3] = hv.w;
        }
        #pragma unroll
        for (int kk = 0; kk < 4; ++kk) {
            const float* wr = W + (size_t)(k + kk) * HID + j0;
            float4 w0 = *(const float4*)(wr);
            float4 w1 = *(const float4*)(wr + 4);
            float w[8] = {w0.x, w0.y, w0.z, w0.w, w1.x, w1.y, w1.z, w1.w};
            #pragma unroll
            for (int r = 0; r < 4; ++r) {
                float hv = h[r][kk];
                #pragma unroll
                for (int c = 0; c < 8; ++c)
                    acc[r][c] = fmaf(hv, w[c], acc[r][c]);
            }
        }
    }
}

__device__ __forceinline__ void mlp_tail(
    float (&A)[NPB][LDP], float (&B)[NPB][LDP], float (&csum)[HID],
    const float (&v)[4][8],
    const float* __restrict__ W1, const float* __restrict__ b1,
    const float* __restrict__ W2, const float* __restrict__ b2,
    const float* __restrict__ W3, const float* __restrict__ b3,
    float* __restrict__ colsum, int n0, int j0, int nbase, int tid)
{
    float acc[4][8];
    {
        float4 bb0 = *(const float4*)(b1 + j0);
        float4 bb1 = *(const float4*)(b1 + j0 + 4);
        #pragma unroll
        for (int r = 0; r < 4; ++r) {
            acc[r][0] = bb0.x; acc[r][1] = bb0.y; acc[r][2] = bb0.z; acc[r][3] = bb0.w;
            acc[r][4] = bb1.x; acc[r][5] = bb1.y; acc[r][6] = bb1.z; acc[r][7] = bb1.w;
        }
    }
    #pragma unroll
    for (int k = 0; k < 8; ++k) {
        const float* wr = W1 + (size_t)k * HID + j0;
        float4 w0 = *(const float4*)(wr);
        float4 w1 = *(const float4*)(wr + 4);
        float w[8] = {w0.x, w0.y, w0.z, w0.w, w1.x, w1.y, w1.z, w1.w};
        #pragma unroll
        for (int r = 0; r < 4; ++r) {
            float hv = v[r][k];
            #pragma unroll
            for (int c = 0; c < 8; ++c) acc[r][c] = fmaf(hv, w[c], acc[r][c]);
        }
    }
    #pragma unroll
    for (int r = 0; r < 4; ++r) {
        float4 o0 = make_float4(fmaxf(acc[r][0], 0.f), fmaxf(acc[r][1], 0.f),
                                fmaxf(acc[r][2], 0.f), fmaxf(acc[r][3], 0.f));
        float4 o1 = make_float4(fmaxf(acc[r][4], 0.f), fmaxf(acc[r][5], 0.f),
                                fmaxf(acc[r][6], 0.f), fmaxf(acc[r][7], 0.f));
        *(float4*)&A[n0 + r][j0]     = o0;
        *(float4*)&A[n0 + r][j0 + 4] = o1;
    }
    __syncthreads();

    matvec128(A, W2, b2, n0, j0, acc);
    #pragma unroll
    for (int r = 0; r < 4; ++r) {
        float4 o0 = make_float4(fmaxf(acc[r][0], 0.f), fmaxf(acc[r][1], 0.f),
                                fmaxf(acc[r][2], 0.f), fmaxf(acc[r][3], 0.f));
        float4 o1 = make_float4(fmaxf(acc[r][4], 0.f), fmaxf(acc[r][5], 0.f),
                                fmaxf(acc[r][6], 0.f), fmaxf(acc[r][7], 0.f));
        *(float4*)&B[n0 + r][j0]     = o0;
        *(float4*)&B[n0 + r][j0 + 4] = o1;
    }
    __syncthreads();

    matvec128(B, W3, b3, n0, j0, acc);

    float part[8];
    #pragma unroll
    for (int c = 0; c < 8; ++c) part[c] = 0.0f;
    #pragma unroll
    for (int r = 0; r < 4; ++r) {
        if (nbase + n0 + r < N_NODES) {
            #pragma unroll
            for (int c = 0; c < 8; ++c) part[c] += fmaxf(acc[r][c], 0.f);
        }
    }
    #pragma unroll
    for (int c = 0; c < 8; ++c) atomicAdd(&csum[j0 + c], part[c]);
    __syncthreads();
    if (tid < HID) atomicAdd(colsum + tid, csum[tid]);
}

// ---------------- fast path MLP: fused neighbor gather + 3-layer MLP -------
__global__ __launch_bounds__(256, 2) void k_mlp_fused(
    const float4* __restrict__ x4,
    const int* __restrict__ cnt, const int* __restrict__ adj,
    const float4* __restrict__ agg_extra4,
    const float* __restrict__ W1, const float* __restrict__ b1,
    const float* __restrict__ W2, const float* __restrict__ b2,
    const float* __restrict__ W3, const float* __restrict__ b3,
    float* __restrict__ colsum)
{
    __shared__ float A[NPB][LDP];
    __shared__ float B[NPB][LDP];
    __shared__ float csum[HID];
    __shared__ float AG[NPB][12];   // [0..7]=agg sum, [8]=1/deg

    int tid = threadIdx.x;
    int nbase = blockIdx.x * NPB;
    if (tid < HID) csum[tid] = 0.0f;

    // ---- gather phase: 4 lanes per node
    {
        int nn  = tid >> 2;       // 0..63
        int sub = tid & 3;
        int gn  = nbase + nn;
        float s[8];
        #pragma unroll
        for (int c = 0; c < 8; ++c) s[c] = 0.0f;
        int degN = 0;
        if (gn < N_NODES) {
            degN = cnt[gn];
            int m = degN < CAP ? degN : CAP;
            const int* row = adj + (size_t)gn * CAP;
            for (int i = sub; i < m; i += 4) {
                int d = row[i];
                float4 a = x4[(size_t)2 * d];
                float4 b = x4[(size_t)2 * d + 1];
                s[0] += a.x; s[1] += a.y; s[2] += a.z; s[3] += a.w;
                s[4] += b.x; s[5] += b.y; s[6] += b.z; s[7] += b.w;
            }
        }
        #pragma unroll
        for (int c = 0; c < 8; ++c) {
            s[c] += __shfl_xor(s[c], 1, 64);
            s[c] += __shfl_xor(s[c], 2, 64);
        }
        if (sub == 0 && gn < N_NODES) {
            float4 e0 = agg_extra4[(size_t)2 * gn];
            float4 e1 = agg_extra4[(size_t)2 * gn + 1];
            AG[nn][0] = s[0] + e0.x; AG[nn][1] = s[1] + e0.y;
            AG[nn][2] = s[2] + e0.z; AG[nn][3] = s[3] + e0.w;
            AG[nn][4] = s[4] + e1.x; AG[nn][5] = s[5] + e1.y;
            AG[nn][6] = s[6] + e1.z; AG[nn][7] = s[7] + e1.w;
            AG[nn][8] = 1.0f / fmaxf((float)degN, 1.0f);
        }
    }
    __syncthreads();

    // ---- layer 1 inputs: v = x + agg/deg
    int cidx = tid & 15;
    int nidx = tid >> 4;
    int j0 = cidx * 8;
    int n0 = nidx * 4;

    float v[4][8];
    #pragma unroll
    for (int r = 0; r < 4; ++r) {
        int gn = nbase + n0 + r;
        if (gn < N_NODES) {
            float4 xa = x4[(size_t)2 * gn], xb = x4[(size_t)2 * gn + 1];
            float rd = AG[n0 + r][8];
            v[r][0] = xa.x + AG[n0 + r][0] * rd; v[r][1] = xa.y + AG[n0 + r][1] * rd;
            v[r][2] = xa.z + AG[n0 + r][2] * rd; v[r][3] = xa.w + AG[n0 + r][3] * rd;
            v[r][4] = xb.x + AG[n0 + r][4] * rd; v[r][5] = xb.y + AG[n0 + r][5] * rd;
            v[r][6] = xb.z + AG[n0 + r][6] * rd; v[r][7] = xb.w + AG[n0 + r][7] * rd;
        } else {
            #pragma unroll
            for (int k = 0; k < 8; ++k) v[r][k] = 0.0f;
        }
    }
    mlp_tail(A, B, csum, v, W1, b1, W2, b2, W3, b3, colsum, n0, j0, nbase, tid);
}

// ---------------- fallback MLP: agg from global ----------------------------
__global__ __launch_bounds__(256, 2) void k_mlp(
    const float4* __restrict__ x4, const float4* __restrict__ agg4,
    const float* __restrict__ deg,
    const float* __restrict__ W1, const float* __restrict__ b1,
    const float* __restrict__ W2, const float* __restrict__ b2,
    const float* __restrict__ W3, const float* __restrict__ b3,
    float* __restrict__ colsum)
{
    __shared__ float A[NPB][LDP];
    __shared__ float B[NPB][LDP];
    __shared__ float csum[HID];

    int tid  = threadIdx.x;
    int cidx = tid & 15;
    int nidx = tid >> 4;
    int j0 = cidx * 8;
    int n0 = nidx * 4;
    int nbase = blockIdx.x * NPB;

    if (tid < HID) csum[tid] = 0.0f;

    float v[4][8];
    #pragma unroll
    for (int r = 0; r < 4; ++r) {
        int gn = nbase + n0 + r;
        if (gn < N_NODES) {
            float4 xa = x4[(size_t)2 * gn], xb = x4[(size_t)2 * gn + 1];
            float4 aa = agg4[(size_t)2 * gn], ab = agg4[(size_t)2 * gn + 1];
            float rd = 1.0f / fmaxf(deg[gn], 1.0f);
            v[r][0] = xa.x + aa.x * rd; v[r][1] = xa.y + aa.y * rd;
            v[r][2] = xa.z + aa.z * rd; v[r][3] = xa.w + aa.w * rd;
            v[r][4] = xb.x + ab.x * rd; v[r][5] = xb.y + ab.y * rd;
            v[r][6] = xb.z + ab.z * rd; v[r][7] = xb.w + ab.w * rd;
        } else {
            #pragma unroll
            for (int k = 0; k < 8; ++k) v[r][k] = 0.0f;
        }
    }
    __syncthreads();
    mlp_tail(A, B, csum, v, W1, b1, W2, b2, W3, b3, colsum, n0, j0, nbase, tid);
}

__global__ void k_final(const float* __restrict__ colsum,
                        const float* __restrict__ Wv, const float* __restrict__ bv,
                        float* __restrict__ out)
{
    __shared__ float red[2];
    int t = threadIdx.x;  // 128 threads
    float vv = colsum[t] * (1.0f / (float)N_NODES) * Wv[t];
    #pragma unroll
    for (int m = 32; m >= 1; m >>= 1) vv += __shfl_xor(vv, m, 64);
    if ((t & 63) == 0) red[t >> 6] = vv;
    __syncthreads();
    if (t == 0) out[0] = tanhf(red[0] + red[1] + bv[0]);
}

extern "C" void kernel_launch(void* const* d_in, const int* in_sizes, int n_in,
                              void* d_out, int out_size, void* d_ws, size_t ws_size,
                              hipStream_t stream)
{
    const float* x  = (const float*)d_in[0];
    const int*   ei = (const int*)d_in[1];
    const float* W1 = (const float*)d_in[2];
    const float* b1 = (const float*)d_in[3];
    const float* W2 = (const float*)d_in[4];
    const float* b2 = (const float*)d_in[5];
    const float* W3 = (const float*)d_in[6];
    const float* b3 = (const float*)d_in[7];
    const float* Wv = (const float*)d_in[8];
    const float* bv = (const float*)d_in[9];
    float* out = (float*)d_out;

    char* ws = (char*)d_ws;
    const size_t OFF_CNT = 0;
    const size_t OFF_COLSUM = 2000000;
    const size_t OFF_EXTRA = 2000512;
    const size_t OFF_ADJ = 18000512;
    const size_t WS_NEED = 146000512;

    if (ws_size >= WS_NEED) {
        int*   cnt    = (int*)(ws + OFF_CNT);
        float* colsum = (float*)(ws + OFF_COLSUM);
        float* extra  = (float*)(ws + OFF_EXTRA);
        int*   adj    = (int*)(ws + OFF_ADJ);

        hipMemsetAsync(ws, 0, OFF_ADJ, stream);  // cnt + colsum + extra

        k_build<<<(N_EDGES + 255) / 256, 256, 0, stream>>>(
            ei, (const float4*)x, cnt, adj, extra);

        k_mlp_fused<<<(N_NODES + NPB - 1) / NPB, 256, 0, stream>>>(
            (const float4*)x, cnt, adj, (const float4*)extra,
            W1, b1, W2, b2, W3, b3, colsum);

        k_final<<<1, 128, 0, stream>>>(colsum, Wv, bv, out);
    } else {
        float* agg    = (float*)(ws);
        float* deg    = (float*)(ws + (size_t)N_NODES * 8 * 4);
        float* colsum = (float*)(ws + (size_t)N_NODES * 8 * 4 + (size_t)N_NODES * 4);
        size_t zero_bytes = (size_t)N_NODES * 8 * 4 + (size_t)N_NODES * 4 + HID * 4;

        hipMemsetAsync(d_ws, 0, zero_bytes, stream);

        k_scatter<<<(N_EDGES + 255) / 256, 256, 0, stream>>>(
            ei, (const float4*)x, agg, deg);

        k_mlp<<<(N_NODES + NPB - 1) / NPB, 256, 0, stream>>>(
            (const float4*)x, (const float4*)agg, deg,
            W1, b1, W2, b2, W3, b3, colsum);

        k_final<<<1, 128, 0, stream>>>(colsum, Wv, bv, out);
    }
}

// Round 3
// 984.864 us; speedup vs baseline: 4.3074x; 1.4618x over previous
//
#include <hip/hip_runtime.h>
#include <hip/hip_bf16.h>

#define N_NODES 500000
#define N_EDGES 8000000
#define HID 128
#define NPB 64       // nodes per block in MLP kernel
#define LDP 132      // padded LDS row (floats)

#define BSH 9        // 512 nodes per bucket
#define BNODES 512
#define NBUCK 977    // ceil(500000/512)
#define CAPB 9216    // slots per bucket region (mean 8192, sd ~90 -> 11 sigma slack)
#define EPB 16384    // edges per binning block
#define DSTMASK 0x7FFFFu

// ---------------------------------------------------------------------------
// Fast-path workspace layout (bytes), needs 72,020,736 (ws is >=146MB):
//   [0, 4,096)                    gcnt      int[NBUCK]        (zeroed)
//   [4,096, 4,608)                colsum    float[128]        (zeroed)
//   [4,608, 2,004,608)            deg_extra float[N_NODES]    (zeroed)
//   [2,004,608, 18,004,608)       agg_extra float[N_NODES*8]  (zeroed)
//   [18,004,608, 54,020,736)      region    u32[NBUCK*CAPB]   (no zero)
//   [54,020,736, 70,020,736)      agg       float[N_NODES*8]  (no zero)
//   [70,020,736, 72,020,736)      degf      float[N_NODES]    (no zero)
// Fallback layout (18,000,512 B): agg[N*8] | deg[N] | colsum[128]
// ---------------------------------------------------------------------------

// ---- phase 1: bin edges by src bucket; ~478K global atomics total ---------
__global__ __launch_bounds__(256) void k_bin(
    const int* __restrict__ ei, const float4* __restrict__ x4,
    int* __restrict__ gcnt, unsigned* __restrict__ region,
    float* __restrict__ agg_extra, float* __restrict__ deg_extra)
{
    __shared__ int cntA[NBUCK];
    __shared__ int baseB[NBUCK];
    int tid = threadIdx.x;
    for (int b = tid; b < NBUCK; b += 256) cntA[b] = 0;
    __syncthreads();
    int e0 = blockIdx.x * EPB;

    // pass A: per-block bucket histogram (LDS atomics)
    #pragma unroll 4
    for (int k = 0; k < EPB / 256; ++k) {
        int e = e0 + k * 256 + tid;
        if (e < N_EDGES) {
            int s = ei[e];
            atomicAdd(&cntA[s >> BSH], 1);
        }
    }
    __syncthreads();

    // reserve global ranges: one global atomic per (block, bucket)
    for (int b = tid; b < NBUCK; b += 256) {
        int c = cntA[b];
        baseB[b] = (c > 0) ? atomicAdd(&gcnt[b], c) : 0;
        cntA[b] = 0;
    }
    __syncthreads();

    // pass B: place edges at base + local position
    #pragma unroll 4
    for (int k = 0; k < EPB / 256; ++k) {
        int e = e0 + k * 256 + tid;
        if (e < N_EDGES) {
            int s = ei[e];
            int d = ei[N_EDGES + e];
            int b = s >> BSH;
            int pos = atomicAdd(&cntA[b], 1);
            int slot = baseB[b] + pos;
            if (slot < CAPB) {
                region[(size_t)b * CAPB + slot] =
                    ((unsigned)(s & (BNODES - 1)) << 19) | (unsigned)d;
            } else {
                // exact overflow fallback (statistically never taken)
                float4 a = x4[(size_t)2 * d];
                float4 bb = x4[(size_t)2 * d + 1];
                float* p = agg_extra + (size_t)s * 8;
                atomicAdd(p + 0, a.x); atomicAdd(p + 1, a.y);
                atomicAdd(p + 2, a.z); atomicAdd(p + 3, a.w);
                atomicAdd(p + 4, bb.x); atomicAdd(p + 5, bb.y);
                atomicAdd(p + 6, bb.z); atomicAdd(p + 7, bb.w);
                atomicAdd(deg_extra + s, 1.0f);
            }
        }
    }
}

// ---- phase 2: per-bucket gather + LDS accumulate, coalesced write-out -----
__global__ __launch_bounds__(256) void k_gather(
    const unsigned* __restrict__ region, const int* __restrict__ gcnt,
    const float4* __restrict__ x4,
    const float4* __restrict__ agg_extra4, const float* __restrict__ deg_extra,
    float4* __restrict__ agg4, float* __restrict__ degf)
{
    __shared__ float aggL[BNODES * 8];   // 16 KB
    __shared__ int degL[BNODES];         // 2 KB
    int tid = threadIdx.x;
    int b = blockIdx.x;
    for (int i = tid; i < BNODES * 8; i += 256) aggL[i] = 0.0f;
    for (int i = tid; i < BNODES; i += 256) degL[i] = 0;
    __syncthreads();

    int ne = gcnt[b];
    if (ne > CAPB) ne = CAPB;
    const unsigned* reg = region + (size_t)b * CAPB;
    for (int i = tid; i < ne; i += 256) {
        unsigned p = reg[i];
        int d  = (int)(p & DSTMASK);
        int ls = (int)(p >> 19);
        float4 a = x4[(size_t)2 * d];
        float4 bb = x4[(size_t)2 * d + 1];
        float* q = aggL + ls * 8;
        atomicAdd(q + 0, a.x); atomicAdd(q + 1, a.y);
        atomicAdd(q + 2, a.z); atomicAdd(q + 3, a.w);
        atomicAdd(q + 4, bb.x); atomicAdd(q + 5, bb.y);
        atomicAdd(q + 6, bb.z); atomicAdd(q + 7, bb.w);
        atomicAdd(&degL[ls], 1);
    }
    __syncthreads();

    for (int n = tid; n < BNODES; n += 256) {
        int gn = b * BNODES + n;
        if (gn < N_NODES) {
            float4 e0 = agg_extra4[(size_t)2 * gn];
            float4 e1 = agg_extra4[(size_t)2 * gn + 1];
            agg4[(size_t)2 * gn] = make_float4(
                aggL[n * 8 + 0] + e0.x, aggL[n * 8 + 1] + e0.y,
                aggL[n * 8 + 2] + e0.z, aggL[n * 8 + 3] + e0.w);
            agg4[(size_t)2 * gn + 1] = make_float4(
                aggL[n * 8 + 4] + e1.x, aggL[n * 8 + 5] + e1.y,
                aggL[n * 8 + 6] + e1.z, aggL[n * 8 + 7] + e1.w);
            degf[gn] = (float)degL[n] + deg_extra[gn];
        }
    }
}

// ---- fallback: original feature scatter -----------------------------------
__global__ __launch_bounds__(256) void k_scatter(
    const int* __restrict__ ei, const float4* __restrict__ x4,
    float* __restrict__ agg, float* __restrict__ deg)
{
    int e = blockIdx.x * 256 + threadIdx.x;
    if (e >= N_EDGES) return;
    int s = ei[e];
    int d = ei[N_EDGES + e];
    atomicAdd(deg + s, 1.0f);
    float4 a = x4[(size_t)2 * d];
    float4 b = x4[(size_t)2 * d + 1];
    float* p = agg + (size_t)s * 8;
    atomicAdd(p + 0, a.x); atomicAdd(p + 1, a.y);
    atomicAdd(p + 2, a.z); atomicAdd(p + 3, a.w);
    atomicAdd(p + 4, b.x); atomicAdd(p + 5, b.y);
    atomicAdd(p + 6, b.z); atomicAdd(p + 7, b.w);
}

// 128->128 matvec for a 4-node x 8-col register tile, Hin from LDS
__device__ __forceinline__ void matvec128(
    const float (&Hin)[NPB][LDP],
    const float* __restrict__ W, const float* __restrict__ bias,
    int n0, int j0, float (&acc)[4][8])
{
    {
        float4 bb0 = *(const float4*)(bias + j0);
        float4 bb1 = *(const float4*)(bias + j0 + 4);
        #pragma unroll
        for (int r = 0; r < 4; ++r) {
            acc[r][0] = bb0.x; acc[r][1] = bb0.y; acc[r][2] = bb0.z; acc[r][3] = bb0.w;
            acc[r][4] = bb1.x; acc[r][5] = bb1.y; acc[r][6] = bb1.z; acc[r][7] = bb1.w;
        }
    }
    for (int k = 0; k < 128; k += 4) {
        float h[4][4];
        #pragma unroll
        for (int r = 0; r < 4; ++r) {
            float4 hv = *(const float4*)&Hin[n0 + r][k];
            h[r][0] = hv.x; h[r][1] = hv.y; h[r][2] = hv.z; h[r][3] = hv.w;
        }
        #pragma unroll
        for (int kk = 0; kk < 4; ++kk) {
            const float* wr = W + (size_t)(k + kk) * HID + j0;
            float4 w0 = *(const float4*)(wr);
            float4 w1 = *(const float4*)(wr + 4);
            float w[8] = {w0.x, w0.y, w0.z, w0.w, w1.x, w1.y, w1.z, w1.w};
            #pragma unroll
            for (int r = 0; r < 4; ++r) {
                float hv = h[r][kk];
                #pragma unroll
                for (int c = 0; c < 8; ++c)
                    acc[r][c] = fmaf(hv, w[c], acc[r][c]);
            }
        }
    }
}

// ---- fused 3-layer MLP + column-sum; single in-place LDS buffer -----------
__global__ __launch_bounds__(256, 4) void k_mlp(
    const float4* __restrict__ x4, const float4* __restrict__ agg4,
    const float* __restrict__ degf,
    const float* __restrict__ W1, const float* __restrict__ b1,
    const float* __restrict__ W2, const float* __restrict__ b2,
    const float* __restrict__ W3, const float* __restrict__ b3,
    float* __restrict__ colsum)
{
    __shared__ float A[NPB][LDP];    // 33.8 KB, reused across layers
    __shared__ float csum[HID];

    int tid  = threadIdx.x;
    int cidx = tid & 15;
    int nidx = tid >> 4;
    int j0 = cidx * 8;
    int n0 = nidx * 4;
    int nbase = blockIdx.x * NPB;

    if (tid < HID) csum[tid] = 0.0f;

    // layer-1 inputs: v = x + agg/deg
    float v[4][8];
    #pragma unroll
    for (int r = 0; r < 4; ++r) {
        int gn = nbase + n0 + r;
        if (gn < N_NODES) {
            float4 xa = x4[(size_t)2 * gn], xb = x4[(size_t)2 * gn + 1];
            float4 aa = agg4[(size_t)2 * gn], ab = agg4[(size_t)2 * gn + 1];
            float rd = 1.0f / fmaxf(degf[gn], 1.0f);
            v[r][0] = xa.x + aa.x * rd; v[r][1] = xa.y + aa.y * rd;
            v[r][2] = xa.z + aa.z * rd; v[r][3] = xa.w + aa.w * rd;
            v[r][4] = xb.x + ab.x * rd; v[r][5] = xb.y + ab.y * rd;
            v[r][6] = xb.z + ab.z * rd; v[r][7] = xb.w + ab.w * rd;
        } else {
            #pragma unroll
            for (int k = 0; k < 8; ++k) v[r][k] = 0.0f;
        }
    }

    // ---- layer 1: h1 = relu(v @ W1 + b1) -> A
    float acc[4][8];
    {
        float4 bb0 = *(const float4*)(b1 + j0);
        float4 bb1 = *(const float4*)(b1 + j0 + 4);
        #pragma unroll
        for (int r = 0; r < 4; ++r) {
            acc[r][0] = bb0.x; acc[r][1] = bb0.y; acc[r][2] = bb0.z; acc[r][3] = bb0.w;
            acc[r][4] = bb1.x; acc[r][5] = bb1.y; acc[r][6] = bb1.z; acc[r][7] = bb1.w;
        }
    }
    #pragma unroll
    for (int k = 0; k < 8; ++k) {
        const float* wr = W1 + (size_t)k * HID + j0;
        float4 w0 = *(const float4*)(wr);
        float4 w1 = *(const float4*)(wr + 4);
        float w[8] = {w0.x, w0.y, w0.z, w0.w, w1.x, w1.y, w1.z, w1.w};
        #pragma unroll
        for (int r = 0; r < 4; ++r) {
            float hv = v[r][k];
            #pragma unroll
            for (int c = 0; c < 8; ++c) acc[r][c] = fmaf(hv, w[c], acc[r][c]);
        }
    }
    #pragma unroll
    for (int r = 0; r < 4; ++r) {
        *(float4*)&A[n0 + r][j0] = make_float4(
            fmaxf(acc[r][0], 0.f), fmaxf(acc[r][1], 0.f),
            fmaxf(acc[r][2], 0.f), fmaxf(acc[r][3], 0.f));
        *(float4*)&A[n0 + r][j0 + 4] = make_float4(
            fmaxf(acc[r][4], 0.f), fmaxf(acc[r][5], 0.f),
            fmaxf(acc[r][6], 0.f), fmaxf(acc[r][7], 0.f));
    }
    __syncthreads();

    // ---- layer 2: read A fully into acc, then overwrite A in place
    matvec128(A, W2, b2, n0, j0, acc);
    __syncthreads();
    #pragma unroll
    for (int r = 0; r < 4; ++r) {
        *(float4*)&A[n0 + r][j0] = make_float4(
            fmaxf(acc[r][0], 0.f), fmaxf(acc[r][1], 0.f),
            fmaxf(acc[r][2], 0.f), fmaxf(acc[r][3], 0.f));
        *(float4*)&A[n0 + r][j0 + 4] = make_float4(
            fmaxf(acc[r][4], 0.f), fmaxf(acc[r][5], 0.f),
            fmaxf(acc[r][6], 0.f), fmaxf(acc[r][7], 0.f));
    }
    __syncthreads();

    // ---- layer 3: h3 = relu(h2 @ W3 + b3), reduced in registers
    matvec128(A, W3, b3, n0, j0, acc);

    float part[8];
    #pragma unroll
    for (int c = 0; c < 8; ++c) part[c] = 0.0f;
    #pragma unroll
    for (int r = 0; r < 4; ++r) {
        if (nbase + n0 + r < N_NODES) {
            #pragma unroll
            for (int c = 0; c < 8; ++c) part[c] += fmaxf(acc[r][c], 0.f);
        }
    }
    #pragma unroll
    for (int c = 0; c < 8; ++c) atomicAdd(&csum[j0 + c], part[c]);
    __syncthreads();
    if (tid < HID) atomicAdd(colsum + tid, csum[tid]);
}

__global__ void k_final(const float* __restrict__ colsum,
                        const float* __restrict__ Wv, const float* __restrict__ bv,
                        float* __restrict__ out)
{
    __shared__ float red[2];
    int t = threadIdx.x;  // 128 threads
    float vv = colsum[t] * (1.0f / (float)N_NODES) * Wv[t];
    #pragma unroll
    for (int m = 32; m >= 1; m >>= 1) vv += __shfl_xor(vv, m, 64);
    if ((t & 63) == 0) red[t >> 6] = vv;
    __syncthreads();
    if (t == 0) out[0] = tanhf(red[0] + red[1] + bv[0]);
}

extern "C" void kernel_launch(void* const* d_in, const int* in_sizes, int n_in,
                              void* d_out, int out_size, void* d_ws, size_t ws_size,
                              hipStream_t stream)
{
    const float* x  = (const float*)d_in[0];
    const int*   ei = (const int*)d_in[1];
    const float* W1 = (const float*)d_in[2];
    const float* b1 = (const float*)d_in[3];
    const float* W2 = (const float*)d_in[4];
    const float* b2 = (const float*)d_in[5];
    const float* W3 = (const float*)d_in[6];
    const float* b3 = (const float*)d_in[7];
    const float* Wv = (const float*)d_in[8];
    const float* bv = (const float*)d_in[9];
    float* out = (float*)d_out;

    char* ws = (char*)d_ws;
    const size_t OFF_GCNT   = 0;
    const size_t OFF_COLSUM = 4096;
    const size_t OFF_DEGX   = 4608;
    const size_t OFF_AGGX   = 2004608;
    const size_t OFF_REGION = 18004608;
    const size_t OFF_AGG    = 54020736;
    const size_t OFF_DEGF   = 70020736;
    const size_t WS_NEED    = 72020736;

    if (ws_size >= WS_NEED) {
        int*      gcnt   = (int*)(ws + OFF_GCNT);
        float*    colsum = (float*)(ws + OFF_COLSUM);
        float*    degx   = (float*)(ws + OFF_DEGX);
        float*    aggx   = (float*)(ws + OFF_AGGX);
        unsigned* region = (unsigned*)(ws + OFF_REGION);
        float*    agg    = (float*)(ws + OFF_AGG);
        float*    degf   = (float*)(ws + OFF_DEGF);

        hipMemsetAsync(ws, 0, OFF_REGION, stream);  // gcnt+colsum+extras

        k_bin<<<(N_EDGES + EPB - 1) / EPB, 256, 0, stream>>>(
            ei, (const float4*)x, gcnt, region, aggx, degx);

        k_gather<<<NBUCK, 256, 0, stream>>>(
            region, gcnt, (const float4*)x,
            (const float4*)aggx, degx, (float4*)agg, degf);

        k_mlp<<<(N_NODES + NPB - 1) / NPB, 256, 0, stream>>>(
            (const float4*)x, (const float4*)agg, degf,
            W1, b1, W2, b2, W3, b3, colsum);

        k_final<<<1, 128, 0, stream>>>(colsum, Wv, bv, out);
    } else {
        float* agg    = (float*)(ws);
        float* deg    = (float*)(ws + (size_t)N_NODES * 8 * 4);
        float* colsum = (float*)(ws + (size_t)N_NODES * 8 * 4 + (size_t)N_NODES * 4);
        size_t zero_bytes = (size_t)N_NODES * 8 * 4 + (size_t)N_NODES * 4 + HID * 4;

        hipMemsetAsync(d_ws, 0, zero_bytes, stream);

        k_scatter<<<(N_EDGES + 255) / 256, 256, 0, stream>>>(
            ei, (const float4*)x, agg, deg);

        k_mlp<<<(N_NODES + NPB - 1) / NPB, 256, 0, stream>>>(
            (const float4*)x, (const float4*)agg, deg,
            W1, b1, W2, b2, W3, b3, colsum);

        k_final<<<1, 128, 0, stream>>>(colsum, Wv, bv, out);
    }
}

// Round 4
// 612.315 us; speedup vs baseline: 6.9281x; 1.6084x over previous
//
#include <hip/hip_runtime.h>
#include <hip/hip_bf16.h>

#define N_NODES 500000
#define N_EDGES 8000000
#define HID 128
#define NPB 64       // nodes per block in fallback MLP kernel
#define LDP 132      // padded LDS row (floats) for fallback

#define BSH 9        // 512 nodes per bucket
#define BNODES 512
#define NBUCK 977    // ceil(500000/512)
#define CAPB 9216    // slots per bucket region
#define EPB 16384    // edges per binning block
#define DSTMASK 0x7FFFFu

#define MNPB 128     // nodes per block in MFMA MLP (4 waves x 32 rows)
#define HPAD 136     // padded H row in bf16 elems (272B: keeps b128 reads at bank floor)

typedef __attribute__((ext_vector_type(8))) short bf16x8;
typedef __attribute__((ext_vector_type(4))) float f32x4;

__device__ __forceinline__ ushort f2bf(float f) {
    unsigned u = __float_as_uint(f);
    return (ushort)((u + 0x7fffu + ((u >> 16) & 1u)) >> 16);   // RNE
}
__device__ __forceinline__ float bf2f(ushort h) {
    return __uint_as_float((unsigned)h << 16);
}

// ---------------------------------------------------------------------------
// Fast-path workspace layout (bytes), needs 72,168,192:
//   [0, 4,096)                 gcnt      int[NBUCK]         (zeroed)
//   [4,096, 4,608)             colsum    float[128]         (zeroed)
//   [4,608, 2,004,608)         deg_extra float[N_NODES]     (zeroed)
//   [2,004,608, 18,004,608)    agg_extra float[N_NODES*8]   (zeroed)
//   [18,004,608, 54,020,736)   region    u32[NBUCK*CAPB]
//   [54,020,736, 70,020,736)   agg       float[N_NODES*8]
//   [70,020,736, 72,020,736)   degf      float[N_NODES]
//   [72,020,736, 72,037,120)   P1 packed W1 bf16 hi/lo frags
//   [72,037,120, 72,102,656)   P2 packed W2
//   [72,102,656, 72,168,192)   P3 packed W3
// ---------------------------------------------------------------------------

// ---- phase 1: bin edges by src bucket -------------------------------------
__global__ __launch_bounds__(256) void k_bin(
    const int* __restrict__ ei, const float4* __restrict__ x4,
    int* __restrict__ gcnt, unsigned* __restrict__ region,
    float* __restrict__ agg_extra, float* __restrict__ deg_extra)
{
    __shared__ int cntA[NBUCK];
    __shared__ int baseB[NBUCK];
    int tid = threadIdx.x;
    for (int b = tid; b < NBUCK; b += 256) cntA[b] = 0;
    __syncthreads();
    int e0 = blockIdx.x * EPB;

    #pragma unroll 4
    for (int k = 0; k < EPB / 256; ++k) {
        int e = e0 + k * 256 + tid;
        if (e < N_EDGES) {
            int s = ei[e];
            atomicAdd(&cntA[s >> BSH], 1);
        }
    }
    __syncthreads();

    for (int b = tid; b < NBUCK; b += 256) {
        int c = cntA[b];
        baseB[b] = (c > 0) ? atomicAdd(&gcnt[b], c) : 0;
        cntA[b] = 0;
    }
    __syncthreads();

    #pragma unroll 4
    for (int k = 0; k < EPB / 256; ++k) {
        int e = e0 + k * 256 + tid;
        if (e < N_EDGES) {
            int s = ei[e];
            int d = ei[N_EDGES + e];
            int b = s >> BSH;
            int pos = atomicAdd(&cntA[b], 1);
            int slot = baseB[b] + pos;
            if (slot < CAPB) {
                region[(size_t)b * CAPB + slot] =
                    ((unsigned)(s & (BNODES - 1)) << 19) | (unsigned)d;
            } else {
                float4 a = x4[(size_t)2 * d];
                float4 bb = x4[(size_t)2 * d + 1];
                float* p = agg_extra + (size_t)s * 8;
                atomicAdd(p + 0, a.x); atomicAdd(p + 1, a.y);
                atomicAdd(p + 2, a.z); atomicAdd(p + 3, a.w);
                atomicAdd(p + 4, bb.x); atomicAdd(p + 5, bb.y);
                atomicAdd(p + 6, bb.z); atomicAdd(p + 7, bb.w);
                atomicAdd(deg_extra + s, 1.0f);
            }
        }
    }
}

// ---- phase 2: per-bucket gather + LDS accumulate --------------------------
__global__ __launch_bounds__(256) void k_gather(
    const unsigned* __restrict__ region, const int* __restrict__ gcnt,
    const float4* __restrict__ x4,
    const float4* __restrict__ agg_extra4, const float* __restrict__ deg_extra,
    float4* __restrict__ agg4, float* __restrict__ degf)
{
    __shared__ float aggL[BNODES * 8];
    __shared__ int degL[BNODES];
    int tid = threadIdx.x;
    int b = blockIdx.x;
    for (int i = tid; i < BNODES * 8; i += 256) aggL[i] = 0.0f;
    for (int i = tid; i < BNODES; i += 256) degL[i] = 0;
    __syncthreads();

    int ne = gcnt[b];
    if (ne > CAPB) ne = CAPB;
    const unsigned* reg = region + (size_t)b * CAPB;
    for (int i = tid; i < ne; i += 256) {
        unsigned p = reg[i];
        int d  = (int)(p & DSTMASK);
        int ls = (int)(p >> 19);
        float4 a = x4[(size_t)2 * d];
        float4 bb = x4[(size_t)2 * d + 1];
        float* q = aggL + ls * 8;
        atomicAdd(q + 0, a.x); atomicAdd(q + 1, a.y);
        atomicAdd(q + 2, a.z); atomicAdd(q + 3, a.w);
        atomicAdd(q + 4, bb.x); atomicAdd(q + 5, bb.y);
        atomicAdd(q + 6, bb.z); atomicAdd(q + 7, bb.w);
        atomicAdd(&degL[ls], 1);
    }
    __syncthreads();

    for (int n = tid; n < BNODES; n += 256) {
        int gn = b * BNODES + n;
        if (gn < N_NODES) {
            float4 e0 = agg_extra4[(size_t)2 * gn];
            float4 e1 = agg_extra4[(size_t)2 * gn + 1];
            agg4[(size_t)2 * gn] = make_float4(
                aggL[n * 8 + 0] + e0.x, aggL[n * 8 + 1] + e0.y,
                aggL[n * 8 + 2] + e0.z, aggL[n * 8 + 3] + e0.w);
            agg4[(size_t)2 * gn + 1] = make_float4(
                aggL[n * 8 + 4] + e1.x, aggL[n * 8 + 5] + e1.y,
                aggL[n * 8 + 6] + e1.z, aggL[n * 8 + 7] + e1.w);
            degf[gn] = (float)degL[n] + deg_extra[gn];
        }
    }
}

// ---- pack W into MFMA B-fragment order, split bf16 hi/lo ------------------
// Layout: P[(ks*8+ct)*2 + hl][lane 0..63][j 0..7]  (ushort)
// B frag semantics: lane l holds W[k = ks*32 + (l>>4)*8 + j][col = ct*16 + (l&15)]
__global__ __launch_bounds__(256) void k_pack(
    const float* __restrict__ W1, const float* __restrict__ W2,
    const float* __restrict__ W3,
    ushort* __restrict__ P1, ushort* __restrict__ P2, ushort* __restrict__ P3)
{
    int b = blockIdx.x;
    const float* W = (b == 0) ? W1 : ((b == 1) ? W2 : W3);
    ushort* P = (b == 0) ? P1 : ((b == 1) ? P2 : P3);
    int KS = (b == 0) ? 1 : 4;
    int total = KS * 8 * 64 * 8;
    for (int i = threadIdx.x; i < total; i += 256) {
        int j    = i & 7;
        int lane = (i >> 3) & 63;
        int ct   = (i >> 9) & 7;
        int ks   = i >> 12;
        int k = ks * 32 + (lane >> 4) * 8 + j;
        int c = ct * 16 + (lane & 15);
        float wv = 0.0f;
        if (b == 0) { if (k < 8) wv = W[k * HID + c]; }
        else        { wv = W[k * HID + c]; }
        ushort hi = f2bf(wv);
        float  lo = wv - bf2f(hi);
        P[(((ks * 8 + ct) * 2 + 0) * 64 + lane) * 8 + j] = hi;
        P[(((ks * 8 + ct) * 2 + 1) * 64 + lane) * 8 + j] = f2bf(lo);
    }
}

// ---- one MFMA layer: Hin (LDS, hi/lo bf16) @ W(packed) -> store or reduce -
template<int KS, bool STORE>
__device__ __forceinline__ void mfma_layer(
    ushort (&Hhi)[MNPB][HPAD], ushort (&Hlo)[MNPB][HPAD],
    const ushort* __restrict__ P, const float* __restrict__ bias,
    int rbase, int l, float* csum, int nbase)
{
    const int cl = l & 15;
    const int g  = l >> 4;

    // A fragments for both 16-row tiles of this wave (read before any write)
    bf16x8 Ahi[2][KS], Alo[2][KS];
    #pragma unroll
    for (int rt = 0; rt < 2; ++rt) {
        #pragma unroll
        for (int ks = 0; ks < KS; ++ks) {
            int row = rbase + rt * 16 + cl;
            int col = ks * 32 + g * 8;
            Ahi[rt][ks] = *(const bf16x8*)&Hhi[row][col];
            Alo[rt][ks] = *(const bf16x8*)&Hlo[row][col];
        }
    }

    #pragma unroll
    for (int ct = 0; ct < 8; ++ct) {
        float bv = bias[ct * 16 + cl];
        f32x4 acc0 = {bv, bv, bv, bv};
        f32x4 acc1 = {bv, bv, bv, bv};
        #pragma unroll
        for (int ks = 0; ks < KS; ++ks) {
            const ushort* pb = P + (size_t)(((ks * 8 + ct) * 2) * 64 + l) * 8;
            bf16x8 Bhi = *(const bf16x8*)pb;
            bf16x8 Blo = *(const bf16x8*)(pb + 512);
            acc0 = __builtin_amdgcn_mfma_f32_16x16x32_bf16(Ahi[0][ks], Bhi, acc0, 0, 0, 0);
            acc1 = __builtin_amdgcn_mfma_f32_16x16x32_bf16(Ahi[1][ks], Bhi, acc1, 0, 0, 0);
            acc0 = __builtin_amdgcn_mfma_f32_16x16x32_bf16(Ahi[0][ks], Blo, acc0, 0, 0, 0);
            acc1 = __builtin_amdgcn_mfma_f32_16x16x32_bf16(Ahi[1][ks], Blo, acc1, 0, 0, 0);
            acc0 = __builtin_amdgcn_mfma_f32_16x16x32_bf16(Alo[0][ks], Bhi, acc0, 0, 0, 0);
            acc1 = __builtin_amdgcn_mfma_f32_16x16x32_bf16(Alo[1][ks], Bhi, acc1, 0, 0, 0);
        }
        if (STORE) {
            // C layout: row = g*4 + j (tile-local), col = ct*16 + cl; wave-local rows
            #pragma unroll
            for (int rt = 0; rt < 2; ++rt) {
                f32x4 a = rt ? acc1 : acc0;
                #pragma unroll
                for (int j = 0; j < 4; ++j) {
                    float h = fmaxf(a[j], 0.0f);
                    ushort hb = f2bf(h);
                    int row = rbase + rt * 16 + g * 4 + j;
                    Hhi[row][ct * 16 + cl] = hb;
                    Hlo[row][ct * 16 + cl] = f2bf(h - bf2f(hb));
                }
            }
        } else {
            float part = 0.0f;
            #pragma unroll
            for (int rt = 0; rt < 2; ++rt) {
                f32x4 a = rt ? acc1 : acc0;
                #pragma unroll
                for (int j = 0; j < 4; ++j) {
                    int gn = nbase + rbase + rt * 16 + g * 4 + j;
                    float h = fmaxf(a[j], 0.0f);
                    part += (gn < N_NODES) ? h : 0.0f;
                }
            }
            part += __shfl_xor(part, 16, 64);
            part += __shfl_xor(part, 32, 64);
            if (g == 0) atomicAdd(&csum[ct * 16 + cl], part);
        }
    }
}

// ---- fused 3-layer MLP via split-bf16 MFMA + column-sum -------------------
__global__ __launch_bounds__(256, 2) void k_mlp_mfma(
    const float4* __restrict__ x4, const float4* __restrict__ agg4,
    const float* __restrict__ degf,
    const ushort* __restrict__ P1, const float* __restrict__ b1,
    const ushort* __restrict__ P2, const float* __restrict__ b2,
    const ushort* __restrict__ P3, const float* __restrict__ b3,
    float* __restrict__ colsum)
{
    __shared__ ushort Hhi[MNPB][HPAD];
    __shared__ ushort Hlo[MNPB][HPAD];
    __shared__ float csum[HID];

    const int tid = threadIdx.x;
    const int wv  = tid >> 6;
    const int l   = tid & 63;
    const int rbase = wv * 32;       // wave owns rows [rbase, rbase+32)
    const int nbase = blockIdx.x * MNPB;

    if (tid < HID) csum[tid] = 0.0f;
    __syncthreads();

    // ---- v = x + agg/deg -> H cols 0..7 (hi/lo), cols 8..31 zeroed
    if (l < 32) {
        int rr = l;
        int gn = nbase + rbase + rr;
        float vv[8];
        if (gn < N_NODES) {
            float4 xa = x4[(size_t)2 * gn], xb = x4[(size_t)2 * gn + 1];
            float4 aa = agg4[(size_t)2 * gn], ab = agg4[(size_t)2 * gn + 1];
            float rd = 1.0f / fmaxf(degf[gn], 1.0f);
            vv[0] = xa.x + aa.x * rd; vv[1] = xa.y + aa.y * rd;
            vv[2] = xa.z + aa.z * rd; vv[3] = xa.w + aa.w * rd;
            vv[4] = xb.x + ab.x * rd; vv[5] = xb.y + ab.y * rd;
            vv[6] = xb.z + ab.z * rd; vv[7] = xb.w + ab.w * rd;
        } else {
            #pragma unroll
            for (int j = 0; j < 8; ++j) vv[j] = 0.0f;
        }
        bf16x8 hv, lv;
        #pragma unroll
        for (int j = 0; j < 8; ++j) {
            ushort hb = f2bf(vv[j]);
            hv[j] = (short)hb;
            lv[j] = (short)f2bf(vv[j] - bf2f(hb));
        }
        int row = rbase + rr;
        bf16x8 z = (bf16x8)0;
        *(bf16x8*)&Hhi[row][0]  = hv;
        *(bf16x8*)&Hhi[row][8]  = z;
        *(bf16x8*)&Hhi[row][16] = z;
        *(bf16x8*)&Hhi[row][24] = z;
        *(bf16x8*)&Hlo[row][0]  = lv;
        *(bf16x8*)&Hlo[row][8]  = z;
        *(bf16x8*)&Hlo[row][16] = z;
        *(bf16x8*)&Hlo[row][24] = z;
    }
    // no barrier: all layer dataflow is wave-local (wave reads/writes only its
    // own 32 rows; per-wave LDS ops execute in order)

    mfma_layer<1, true >(Hhi, Hlo, P1, b1, rbase, l, csum, nbase);  // 8 -> 128
    mfma_layer<4, true >(Hhi, Hlo, P2, b2, rbase, l, csum, nbase);  // 128 -> 128
    mfma_layer<4, false>(Hhi, Hlo, P3, b3, rbase, l, csum, nbase);  // 128 -> 128 + reduce

    __syncthreads();
    if (tid < HID) atomicAdd(&colsum[tid], csum[tid]);
}

// ---- fallback path kernels (ws too small): original scatter + vector MLP --
__global__ __launch_bounds__(256) void k_scatter(
    const int* __restrict__ ei, const float4* __restrict__ x4,
    float* __restrict__ agg, float* __restrict__ deg)
{
    int e = blockIdx.x * 256 + threadIdx.x;
    if (e >= N_EDGES) return;
    int s = ei[e];
    int d = ei[N_EDGES + e];
    atomicAdd(deg + s, 1.0f);
    float4 a = x4[(size_t)2 * d];
    float4 b = x4[(size_t)2 * d + 1];
    float* p = agg + (size_t)s * 8;
    atomicAdd(p + 0, a.x); atomicAdd(p + 1, a.y);
    atomicAdd(p + 2, a.z); atomicAdd(p + 3, a.w);
    atomicAdd(p + 4, b.x); atomicAdd(p + 5, b.y);
    atomicAdd(p + 6, b.z); atomicAdd(p + 7, b.w);
}

__device__ __forceinline__ void matvec128(
    const float (&Hin)[NPB][LDP],
    const float* __restrict__ W, const float* __restrict__ bias,
    int n0, int j0, float (&acc)[4][8])
{
    {
        float4 bb0 = *(const float4*)(bias + j0);
        float4 bb1 = *(const float4*)(bias + j0 + 4);
        #pragma unroll
        for (int r = 0; r < 4; ++r) {
            acc[r][0] = bb0.x; acc[r][1] = bb0.y; acc[r][2] = bb0.z; acc[r][3] = bb0.w;
            acc[r][4] = bb1.x; acc[r][5] = bb1.y; acc[r][6] = bb1.z; acc[r][7] = bb1.w;
        }
    }
    for (int k = 0; k < 128; k += 4) {
        float h[4][4];
        #pragma unroll
        for (int r = 0; r < 4; ++r) {
            float4 hv = *(const float4*)&Hin[n0 + r][k];
            h[r][0] = hv.x; h[r][1] = hv.y; h[r][2] = hv.z; h[r][3] = hv.w;
        }
        #pragma unroll
        for (int kk = 0; kk < 4; ++kk) {
            const float* wr = W + (size_t)(k + kk) * HID + j0;
            float4 w0 = *(const float4*)(wr);
            float4 w1 = *(const float4*)(wr + 4);
            float w[8] = {w0.x, w0.y, w0.z, w0.w, w1.x, w1.y, w1.z, w1.w};
            #pragma unroll
            for (int r = 0; r < 4; ++r) {
                float hv = h[r][kk];
                #pragma unroll
                for (int c = 0; c < 8; ++c)
                    acc[r][c] = fmaf(hv, w[c], acc[r][c]);
            }
        }
    }
}

__global__ __launch_bounds__(256, 4) void k_mlp(
    const float4* __restrict__ x4, const float4* __restrict__ agg4,
    const float* __restrict__ degf,
    const float* __restrict__ W1, const float* __restrict__ b1,
    const float* __restrict__ W2, const float* __restrict__ b2,
    const float* __restrict__ W3, const float* __restrict__ b3,
    float* __restrict__ colsum)
{
    __shared__ float A[NPB][LDP];
    __shared__ float csum[HID];

    int tid  = threadIdx.x;
    int cidx = tid & 15;
    int nidx = tid >> 4;
    int j0 = cidx * 8;
    int n0 = nidx * 4;
    int nbase = blockIdx.x * NPB;

    if (tid < HID) csum[tid] = 0.0f;

    float v[4][8];
    #pragma unroll
    for (int r = 0; r < 4; ++r) {
        int gn = nbase + n0 + r;
        if (gn < N_NODES) {
            float4 xa = x4[(size_t)2 * gn], xb = x4[(size_t)2 * gn + 1];
            float4 aa = agg4[(size_t)2 * gn], ab = agg4[(size_t)2 * gn + 1];
            float rd = 1.0f / fmaxf(degf[gn], 1.0f);
            v[r][0] = xa.x + aa.x * rd; v[r][1] = xa.y + aa.y * rd;
            v[r][2] = xa.z + aa.z * rd; v[r][3] = xa.w + aa.w * rd;
            v[r][4] = xb.x + ab.x * rd; v[r][5] = xb.y + ab.y * rd;
            v[r][6] = xb.z + ab.z * rd; v[r][7] = xb.w + ab.w * rd;
        } else {
            #pragma unroll
            for (int k = 0; k < 8; ++k) v[r][k] = 0.0f;
        }
    }

    float acc[4][8];
    {
        float4 bb0 = *(const float4*)(b1 + j0);
        float4 bb1 = *(const float4*)(b1 + j0 + 4);
        #pragma unroll
        for (int r = 0; r < 4; ++r) {
            acc[r][0] = bb0.x; acc[r][1] = bb0.y; acc[r][2] = bb0.z; acc[r][3] = bb0.w;
            acc[r][4] = bb1.x; acc[r][5] = bb1.y; acc[r][6] = bb1.z; acc[r][7] = bb1.w;
        }
    }
    #pragma unroll
    for (int k = 0; k < 8; ++k) {
        const float* wr = W1 + (size_t)k * HID + j0;
        float4 w0 = *(const float4*)(wr);
        float4 w1 = *(const float4*)(wr + 4);
        float w[8] = {w0.x, w0.y, w0.z, w0.w, w1.x, w1.y, w1.z, w1.w};
        #pragma unroll
        for (int r = 0; r < 4; ++r) {
            float hv = v[r][k];
            #pragma unroll
            for (int c = 0; c < 8; ++c) acc[r][c] = fmaf(hv, w[c], acc[r][c]);
        }
    }
    #pragma unroll
    for (int r = 0; r < 4; ++r) {
        *(float4*)&A[n0 + r][j0] = make_float4(
            fmaxf(acc[r][0], 0.f), fmaxf(acc[r][1], 0.f),
            fmaxf(acc[r][2], 0.f), fmaxf(acc[r][3], 0.f));
        *(float4*)&A[n0 + r][j0 + 4] = make_float4(
            fmaxf(acc[r][4], 0.f), fmaxf(acc[r][5], 0.f),
            fmaxf(acc[r][6], 0.f), fmaxf(acc[r][7], 0.f));
    }
    __syncthreads();

    matvec128(A, W2, b2, n0, j0, acc);
    __syncthreads();
    #pragma unroll
    for (int r = 0; r < 4; ++r) {
        *(float4*)&A[n0 + r][j0] = make_float4(
            fmaxf(acc[r][0], 0.f), fmaxf(acc[r][1], 0.f),
            fmaxf(acc[r][2], 0.f), fmaxf(acc[r][3], 0.f));
        *(float4*)&A[n0 + r][j0 + 4] = make_float4(
            fmaxf(acc[r][4], 0.f), fmaxf(acc[r][5], 0.f),
            fmaxf(acc[r][6], 0.f), fmaxf(acc[r][7], 0.f));
    }
    __syncthreads();

    matvec128(A, W3, b3, n0, j0, acc);

    float part[8];
    #pragma unroll
    for (int c = 0; c < 8; ++c) part[c] = 0.0f;
    #pragma unroll
    for (int r = 0; r < 4; ++r) {
        if (nbase + n0 + r < N_NODES) {
            #pragma unroll
            for (int c = 0; c < 8; ++c) part[c] += fmaxf(acc[r][c], 0.f);
        }
    }
    #pragma unroll
    for (int c = 0; c < 8; ++c) atomicAdd(&csum[j0 + c], part[c]);
    __syncthreads();
    if (tid < HID) atomicAdd(colsum + tid, csum[tid]);
}

__global__ void k_final(const float* __restrict__ colsum,
                        const float* __restrict__ Wv, const float* __restrict__ bv,
                        float* __restrict__ out)
{
    __shared__ float red[2];
    int t = threadIdx.x;  // 128 threads
    float vv = colsum[t] * (1.0f / (float)N_NODES) * Wv[t];
    #pragma unroll
    for (int m = 32; m >= 1; m >>= 1) vv += __shfl_xor(vv, m, 64);
    if ((t & 63) == 0) red[t >> 6] = vv;
    __syncthreads();
    if (t == 0) out[0] = tanhf(red[0] + red[1] + bv[0]);
}

extern "C" void kernel_launch(void* const* d_in, const int* in_sizes, int n_in,
                              void* d_out, int out_size, void* d_ws, size_t ws_size,
                              hipStream_t stream)
{
    const float* x  = (const float*)d_in[0];
    const int*   ei = (const int*)d_in[1];
    const float* W1 = (const float*)d_in[2];
    const float* b1 = (const float*)d_in[3];
    const float* W2 = (const float*)d_in[4];
    const float* b2 = (const float*)d_in[5];
    const float* W3 = (const float*)d_in[6];
    const float* b3 = (const float*)d_in[7];
    const float* Wv = (const float*)d_in[8];
    const float* bv = (const float*)d_in[9];
    float* out = (float*)d_out;

    char* ws = (char*)d_ws;
    const size_t OFF_GCNT   = 0;
    const size_t OFF_COLSUM = 4096;
    const size_t OFF_DEGX   = 4608;
    const size_t OFF_AGGX   = 2004608;
    const size_t OFF_REGION = 18004608;
    const size_t OFF_AGG    = 54020736;
    const size_t OFF_DEGF   = 70020736;
    const size_t OFF_PACK1  = 72020736;
    const size_t OFF_PACK2  = 72037120;
    const size_t OFF_PACK3  = 72102656;
    const size_t WS_NEED    = 72168192;

    if (ws_size >= WS_NEED) {
        int*      gcnt   = (int*)(ws + OFF_GCNT);
        float*    colsum = (float*)(ws + OFF_COLSUM);
        float*    degx   = (float*)(ws + OFF_DEGX);
        float*    aggx   = (float*)(ws + OFF_AGGX);
        unsigned* region = (unsigned*)(ws + OFF_REGION);
        float*    agg    = (float*)(ws + OFF_AGG);
        float*    degf   = (float*)(ws + OFF_DEGF);
        ushort*   P1     = (ushort*)(ws + OFF_PACK1);
        ushort*   P2     = (ushort*)(ws + OFF_PACK2);
        ushort*   P3     = (ushort*)(ws + OFF_PACK3);

        hipMemsetAsync(ws, 0, OFF_REGION, stream);  // gcnt+colsum+extras

        k_pack<<<3, 256, 0, stream>>>(W1, W2, W3, P1, P2, P3);

        k_bin<<<(N_EDGES + EPB - 1) / EPB, 256, 0, stream>>>(
            ei, (const float4*)x, gcnt, region, aggx, degx);

        k_gather<<<NBUCK, 256, 0, stream>>>(
            region, gcnt, (const float4*)x,
            (const float4*)aggx, degx, (float4*)agg, degf);

        k_mlp_mfma<<<(N_NODES + MNPB - 1) / MNPB, 256, 0, stream>>>(
            (const float4*)x, (const float4*)agg, degf,
            P1, b1, P2, b2, P3, b3, colsum);

        k_final<<<1, 128, 0, stream>>>(colsum, Wv, bv, out);
    } else {
        float* agg    = (float*)(ws);
        float* deg    = (float*)(ws + (size_t)N_NODES * 8 * 4);
        float* colsum = (float*)(ws + (size_t)N_NODES * 8 * 4 + (size_t)N_NODES * 4);
        size_t zero_bytes = (size_t)N_NODES * 8 * 4 + (size_t)N_NODES * 4 + HID * 4;

        hipMemsetAsync(d_ws, 0, zero_bytes, stream);

        k_scatter<<<(N_EDGES + 255) / 256, 256, 0, stream>>>(
            ei, (const float4*)x, agg, deg);

        k_mlp<<<(N_NODES + NPB - 1) / NPB, 256, 0, stream>>>(
            (const float4*)x, (const float4*)agg, deg,
            W1, b1, W2, b2, W3, b3, colsum);

        k_final<<<1, 128, 0, stream>>>(colsum, Wv, bv, out);
    }
}